// Round 3
// baseline (707.357 us; speedup 1.0000x reference)
//
#include <hip/hip_runtime.h>

// Fused TP all-reduce + residual add + RMSNorm (DeepSeek pattern), fp32.
// hs: [TP, TOKENS, HIDDEN], residual: [TOKENS, HIDDEN], w: [HIDDEN]
// out: normed [TOKENS, HIDDEN] ++ residual_out [TOKENS, HIDDEN]
//
// 822 MB mandatory HBM traffic -> ~150 us floor at achievable streaming BW.
// R3 change: 896-thread blocks (PER_T=2, acc=8 VGPR) -> 28 waves/CU occupancy
// for read-latency hiding, vs 16 waves/CU in the 256-thread version.

constexpr int TP      = 4;
constexpr int TOKENS  = 4096;
constexpr int HIDDEN  = 7168;
constexpr float EPS   = 1e-6f;

constexpr int BLOCK   = 896;                     // 14 waves
constexpr int WAVES   = BLOCK / 64;
constexpr int VEC     = 4;                       // float4
constexpr int PER_T   = HIDDEN / (BLOCK * VEC);  // 2 chunks per thread

static_assert(HIDDEN == BLOCK * VEC * PER_T, "exact tiling required");

typedef float f4 __attribute__((ext_vector_type(4)));

__global__ __launch_bounds__(BLOCK, 7)  // 7 waves/EU -> 2 blocks/CU = 28 waves/CU
void fused_allreduce_rmsnorm(const float* __restrict__ hs,
                             const float* __restrict__ residual,
                             const float* __restrict__ w,
                             float* __restrict__ normed,
                             float* __restrict__ res_out) {
    const int row = blockIdx.x;
    const int tid = threadIdx.x;

    const size_t row_off = (size_t)row * HIDDEN;
    const size_t plane4  = (size_t)TOKENS * (HIDDEN / VEC);  // plane stride in f4

    const f4* __restrict__ h4 = (const f4*)(hs + row_off);
    const f4* __restrict__ r4 = (const f4*)(residual + row_off);
    f4* __restrict__ ro4 = (f4*)(res_out + row_off);
    f4* __restrict__ no4 = (f4*)(normed + row_off);
    const f4* __restrict__ w4 = (const f4*)w;

    f4 acc[PER_T];
    // 4 independent accumulators: no serial FMA chain.
    float sx = 0.f, sy = 0.f, sz = 0.f, sw = 0.f;

    #pragma unroll
    for (int i = 0; i < PER_T; ++i) {
        const size_t idx = (size_t)(tid + i * BLOCK);
        f4 a = __builtin_nontemporal_load(&h4[idx]);
        f4 b = __builtin_nontemporal_load(&h4[idx + plane4]);
        f4 c = __builtin_nontemporal_load(&h4[idx + 2 * plane4]);
        f4 d = __builtin_nontemporal_load(&h4[idx + 3 * plane4]);
        f4 r = __builtin_nontemporal_load(&r4[idx]);
        f4 s = a + b + c + d + r;
        acc[i] = s;
        __builtin_nontemporal_store(s, &ro4[idx]);  // residual_out
        sx += s.x * s.x;
        sy += s.y * s.y;
        sz += s.z * s.z;
        sw += s.w * s.w;
    }
    float sumsq = (sx + sy) + (sz + sw);

    // Wave64 shuffle tree, then LDS combine across the 14 waves.
    #pragma unroll
    for (int off = 32; off > 0; off >>= 1)
        sumsq += __shfl_down(sumsq, off);

    __shared__ float wave_sum[WAVES];
    if ((tid & 63) == 0) wave_sum[tid >> 6] = sumsq;
    __syncthreads();

    float total = 0.f;
    #pragma unroll
    for (int i = 0; i < WAVES; ++i) total += wave_sum[i];  // LDS broadcast reads

    const float scale = rsqrtf(total * (1.0f / HIDDEN) + EPS);

    #pragma unroll
    for (int i = 0; i < PER_T; ++i) {
        const size_t idx = (size_t)(tid + i * BLOCK);
        f4 g = w4[idx];          // 28 KB weight: L2-resident, reused by all blocks
        f4 s = acc[i];
        f4 o = s * scale * g;
        __builtin_nontemporal_store(o, &no4[idx]);  // normed
    }
}

extern "C" void kernel_launch(void* const* d_in, const int* in_sizes, int n_in,
                              void* d_out, int out_size, void* d_ws, size_t ws_size,
                              hipStream_t stream) {
    const float* hs       = (const float*)d_in[0];  // [TP, TOKENS, HIDDEN]
    const float* residual = (const float*)d_in[1];  // [TOKENS, HIDDEN]
    const float* w        = (const float*)d_in[2];  // [HIDDEN]

    float* normed  = (float*)d_out;                           // output 0
    float* res_out = (float*)d_out + (size_t)TOKENS * HIDDEN; // output 1

    dim3 grid(TOKENS);
    dim3 block(BLOCK);
    fused_allreduce_rmsnorm<<<grid, block, 0, stream>>>(hs, residual, w, normed, res_out);
}